// Round 1
// baseline (1540.053 us; speedup 1.0000x reference)
//
#include <hip/hip_runtime.h>

#define N_NODES 50000
#define N_EDGES 800000
#define HDIM 128

typedef unsigned short u16;
typedef unsigned int u32;
typedef __attribute__((ext_vector_type(8))) short short8;
typedef __attribute__((ext_vector_type(4))) float f32x4;

__device__ __forceinline__ u16 f2bf(float f) {
    union { float f; u32 u; } v; v.f = f;
    u32 r = v.u + 0x7FFFu + ((v.u >> 16) & 1u);
    return (u16)(r >> 16);
}

__device__ __forceinline__ float bf2f(u16 h) {
    union { u32 u; float f; } v; v.u = ((u32)h) << 16;
    return v.f;
}

// Pack a [128 x 128] row-major f32 matrix (ld=128) into bf16 B-fragments for
// mfma_f32_16x16x32_bf16. Fragment layout: for tile t (16 cols), chunk c (32 k),
// lane holds 8 bf16: B[k = c*32 + (lane>>4)*8 + j][n = t*16 + (lane&15)].
// dst index: (((t + tOff)*4 + c)*64 + lane)*8 + j
__global__ __launch_bounds__(256) void pack_b(const float* __restrict__ src,
                                              u16* __restrict__ dst, int tOff) {
    int f = threadIdx.x + blockIdx.x * 256;
    if (f >= 2048) return;
    int t = f >> 8;
    int c = (f >> 6) & 3;
    int lane = f & 63;
    int q = lane >> 4, n = lane & 15;
    const float* s = src + (size_t)(c * 32 + q * 8) * 128 + t * 16 + n;
    u16* dp = dst + ((((size_t)(t + tOff) * 4 + c) * 64 + lane) * 8);
#pragma unroll
    for (int j = 0; j < 8; ++j) dp[j] = f2bf(s[(size_t)j * 128]);
}

__global__ void build_bias256(const float* __restrict__ be, float* __restrict__ b256) {
    int i = threadIdx.x;
    b256[i] = (i < 128) ? be[i] : 0.f;
}

// out[M, C] = A[M,128] @ B[128, C] + bias;  A f32, B pre-packed bf16 fragments,
// out bf16 (outBf16=1) or f32. One wave = 16-row strip, full C sweep.
__global__ __launch_bounds__(256) void gemm_mfma(const float* __restrict__ A,
                                                 const u16* __restrict__ PB,
                                                 const float* __restrict__ bias,
                                                 void* __restrict__ outp,
                                                 int M, int Ctiles, int outBf16) {
    int tid = threadIdx.x;
    int wave = tid >> 6;
    int lane = tid & 63;
    int strip = blockIdx.x * 4 + wave;
    int row0 = strip * 16;
    if (row0 >= M) return;
    int q = lane >> 4, n = lane & 15;
    int C = Ctiles * 16;

    // A fragments: a[c][j] = A[row0 + (lane&15)][c*32 + q*8 + j]
    short8 a[4];
    const float* ap = A + (size_t)(row0 + n) * 128 + q * 8;
#pragma unroll
    for (int c = 0; c < 4; ++c) {
        f32x4 f0 = *(const f32x4*)(ap + c * 32);
        f32x4 f1 = *(const f32x4*)(ap + c * 32 + 4);
        short8 t;
#pragma unroll
        for (int j = 0; j < 4; ++j) {
            t[j] = (short)f2bf(f0[j]);
            t[4 + j] = (short)f2bf(f1[j]);
        }
        a[c] = t;
    }

    for (int t = 0; t < Ctiles; ++t) {
        f32x4 acc = {0.f, 0.f, 0.f, 0.f};
#pragma unroll
        for (int c = 0; c < 4; ++c) {
            short8 b = *(const short8*)(PB + (((size_t)t * 4 + c) * 64 + lane) * 8);
            acc = __builtin_amdgcn_mfma_f32_16x16x32_bf16(a[c], b, acc, 0, 0, 0);
        }
        int col = t * 16 + n;
        float bv = bias ? bias[col] : 0.f;
#pragma unroll
        for (int r = 0; r < 3 + 1; ++r) {
            int row = row0 + q * 4 + r;
            float v = acc[r] + bv;
            if (outBf16)
                ((u16*)outp)[(size_t)row * C + col] = f2bf(v);
            else
                ((float*)outp)[(size_t)row * C + col] = v;
        }
    }
}

// Fused edge kernel: per 16-edge strip per wave,
//   D = edge_attr[strip] @ W3   (bf16 MFMA, 8 col-tiles)
//   m = silu(D + T1a[dst] + T1b[src]);  atomic agg[dst] += m
// T1 is [N, 256] bf16: cols 0..127 = x@W1+be, cols 128..255 = x@W2.
__global__ __launch_bounds__(256) void edge_fused(const float* __restrict__ EA,
                                                  const u16* __restrict__ PB3,
                                                  const int* __restrict__ srcIdx,
                                                  const int* __restrict__ dstIdx,
                                                  const u16* __restrict__ T1,
                                                  float* __restrict__ agg) {
    int tid = threadIdx.x;
    int wave = tid >> 6;
    int lane = tid & 63;
    int strip = blockIdx.x * 4 + wave;  // grid sized exactly: E/16/4 blocks
    int e0 = strip * 16;
    int q = lane >> 4, n = lane & 15;

    short8 a[4];
    const float* ap = EA + (size_t)(e0 + n) * 128 + q * 8;
#pragma unroll
    for (int c = 0; c < 4; ++c) {
        f32x4 f0 = *(const f32x4*)(ap + c * 32);
        f32x4 f1 = *(const f32x4*)(ap + c * 32 + 4);
        short8 t;
#pragma unroll
        for (int j = 0; j < 4; ++j) {
            t[j] = (short)f2bf(f0[j]);
            t[4 + j] = (short)f2bf(f1[j]);
        }
        a[c] = t;
    }

    int drow[4], srow[4];
#pragma unroll
    for (int r = 0; r < 4; ++r) {
        int e = e0 + q * 4 + r;
        drow[r] = dstIdx[e];
        srow[r] = srcIdx[e];
    }

#pragma unroll
    for (int t = 0; t < 8; ++t) {
        f32x4 acc = {0.f, 0.f, 0.f, 0.f};
#pragma unroll
        for (int c = 0; c < 4; ++c) {
            short8 b = *(const short8*)(PB3 + (((size_t)t * 4 + c) * 64 + lane) * 8);
            acc = __builtin_amdgcn_mfma_f32_16x16x32_bf16(a[c], b, acc, 0, 0, 0);
        }
        int col = t * 16 + n;
#pragma unroll
        for (int r = 0; r < 4; ++r) {
            float g1 = bf2f(T1[(size_t)drow[r] * 256 + col]);        // x[dst]@W1 + be
            float g2 = bf2f(T1[(size_t)srow[r] * 256 + 128 + col]);  // x[src]@W2
            float v = acc[r] + g1 + g2;
            float m = v / (1.f + __expf(-v));  // SiLU
            unsafeAtomicAdd(agg + (size_t)drow[r] * 128 + col, m);
        }
    }
}

// attn_out[src[e]] += h[dst[e]]  (h bf16, attn f32 atomics)
__global__ __launch_bounds__(256) void attn_scatter(const int* __restrict__ srcIdx,
                                                    const int* __restrict__ dstIdx,
                                                    const u16* __restrict__ h,
                                                    float* __restrict__ attn) {
    int tid = threadIdx.x;
    int g = tid >> 6;
    int lane = tid & 63;
    int base = blockIdx.x * 256 + g * 64;
#pragma unroll 4
    for (int i = 0; i < 64; ++i) {
        int e = base + i;
        int d = dstIdx[e];
        int s = srcIdx[e];
        u32 hv = *(const u32*)(h + (size_t)d * 128 + lane * 2);
        float f0 = bf2f((u16)(hv & 0xFFFFu));
        float f1 = bf2f((u16)(hv >> 16));
        float* ap = attn + (size_t)s * 128 + lane * 2;
        unsafeAtomicAdd(ap, f0);
        unsafeAtomicAdd(ap + 1, f1);
    }
}

extern "C" void kernel_launch(void* const* d_in, const int* in_sizes, int n_in,
                              void* d_out, int out_size, void* d_ws, size_t ws_size,
                              hipStream_t stream) {
    const float* x  = (const float*)d_in[0];
    const int* ei   = (const int*)d_in[1];
    const float* ea = (const float*)d_in[2];
    const float* We = (const float*)d_in[3];
    const float* be = (const float*)d_in[4];
    const float* Wg = (const float*)d_in[5];
    const float* bg = (const float*)d_in[6];
    // d_in[7] = Wa, d_in[8] = ba: dead code — softmax over a size-1 axis is 1.0
    const float* Wo = (const float*)d_in[9];
    const float* bo = (const float*)d_in[10];
    float* out = (float*)d_out;

    const int* srcIdx = ei;            // edge_index[0]
    const int* dstIdx = ei + N_EDGES;  // edge_index[1]

    char* ws = (char*)d_ws;
    u16* PB1 = (u16*)(ws + 0);            // 64 KiB: [W1|W2] packed, 16 tiles
    u16* PB3 = (u16*)(ws + 65536);        // 32 KiB
    u16* PBg = (u16*)(ws + 98304);        // 32 KiB
    u16* PBo = (u16*)(ws + 131072);       // 32 KiB
    float* bias256 = (float*)(ws + 163840);
    u16* T1    = (u16*)(ws + 262144);                       // [N,256] bf16, 25.6 MB
    float* attn = (float*)(ws + 262144);                    // alias of T1 (T1 dead after edge_fused)
    float* agg = (float*)(ws + 262144 + 25600000);          // [N,128] f32, 25.6 MB
    u16* hbuf  = (u16*)(ws + 262144 + 51200000);            // [N,128] bf16, 12.8 MB

    hipMemsetAsync(agg, 0, (size_t)N_NODES * HDIM * 4, stream);

    pack_b<<<8, 256, 0, stream>>>(We, PB1, 0);                  // W1 -> tiles 0..7
    pack_b<<<8, 256, 0, stream>>>(We + 128 * 128, PB1, 8);      // W2 -> tiles 8..15
    pack_b<<<8, 256, 0, stream>>>(We + 2 * 128 * 128, PB3, 0);  // W3
    pack_b<<<8, 256, 0, stream>>>(Wg, PBg, 0);
    pack_b<<<8, 256, 0, stream>>>(Wo, PBo, 0);
    build_bias256<<<1, 256, 0, stream>>>(be, bias256);

    // T1 = [x@W1 + be | x@W2]  (bf16)
    gemm_mfma<<<782, 256, 0, stream>>>(x, PB1, bias256, T1, N_NODES, 16, 1);

    // agg[dst] += silu(x[dst]@W1 + x[src]@W2 + edge_attr@W3 + be)
    edge_fused<<<N_EDGES / 64, 256, 0, stream>>>(ea, PB3, srcIdx, dstIdx, T1, agg);

    // h = agg@Wg + bg  (bf16)
    gemm_mfma<<<782, 256, 0, stream>>>(agg, PBg, bg, hbuf, N_NODES, 8, 1);

    hipMemsetAsync(attn, 0, (size_t)N_NODES * HDIM * 4, stream);

    // attn[src] += h[dst]
    attn_scatter<<<N_EDGES / 256, 256, 0, stream>>>(srcIdx, dstIdx, hbuf, attn);

    // out = attn@Wo + bo  (f32)
    gemm_mfma<<<782, 256, 0, stream>>>(attn, PBo, bo, out, N_NODES, 8, 0);

    (void)in_sizes; (void)n_in; (void)out_size; (void)ws_size;
}

// Round 2
// 1289.860 us; speedup vs baseline: 1.1940x; 1.1940x over previous
//
#include <hip/hip_runtime.h>

#define N_NODES 50000
#define N_EDGES 800000
#define HDIM 128

typedef unsigned short u16;
typedef unsigned int u32;
typedef __attribute__((ext_vector_type(8))) short short8;
typedef __attribute__((ext_vector_type(4))) float f32x4;
typedef __attribute__((ext_vector_type(2))) float f32x2;

__device__ __forceinline__ u16 f2bf(float f) {
    union { float f; u32 u; } v; v.f = f;
    u32 r = v.u + 0x7FFFu + ((v.u >> 16) & 1u);
    return (u16)(r >> 16);
}

__device__ __forceinline__ float bf2f(u16 h) {
    union { u32 u; float f; } v; v.u = ((u32)h) << 16;
    return v.f;
}

// ---- weight pre-pack: [128x128] row-major f32 -> bf16 B-fragments ----
// tile t (16 cols), chunk c (32 k): lane holds B[k=c*32+(lane>>4)*8+j][n=t*16+(lane&15)]
__global__ __launch_bounds__(256) void pack_b(const float* __restrict__ src,
                                              u16* __restrict__ dst, int tOff) {
    int f = threadIdx.x + blockIdx.x * 256;
    if (f >= 2048) return;
    int t = f >> 8;
    int c = (f >> 6) & 3;
    int lane = f & 63;
    int q = lane >> 4, n = lane & 15;
    const float* s = src + (size_t)(c * 32 + q * 8) * 128 + t * 16 + n;
    u16* dp = dst + ((((size_t)(t + tOff) * 4 + c) * 64 + lane) * 8);
#pragma unroll
    for (int j = 0; j < 8; ++j) dp[j] = f2bf(s[(size_t)j * 128]);
}

__global__ void build_bias256(const float* __restrict__ be, float* __restrict__ b256) {
    int i = threadIdx.x;
    b256[i] = (i < 128) ? be[i] : 0.f;
}

// ---- counting sort ----
__global__ __launch_bounds__(256) void hist_kernel(const int* __restrict__ srcIdx,
                                                   const int* __restrict__ dstIdx,
                                                   int* __restrict__ degD,
                                                   int* __restrict__ degS) {
    int e = blockIdx.x * 256 + threadIdx.x;
    if (e >= N_EDGES) return;
    atomicAdd(&degD[dstIdx[e]], 1);
    atomicAdd(&degS[srcIdx[e]], 1);
}

// 1 block, 256 threads: exclusive scan of deg[N] -> off[N+1], cur[N]=off[N]
__global__ __launch_bounds__(256) void scan_kernel(const int* __restrict__ deg,
                                                   int* __restrict__ off,
                                                   int* __restrict__ cur) {
    __shared__ int buf[256];
    const int CHUNK = 196;  // 256*196 = 50176 >= 50000
    int tid = threadIdx.x;
    int s0 = tid * CHUNK, s1 = s0 + CHUNK;
    if (s1 > N_NODES) s1 = N_NODES;
    int s = 0;
    for (int i = s0; i < s1; ++i) s += deg[i];
    buf[tid] = s;
    __syncthreads();
    for (int o = 1; o < 256; o <<= 1) {
        int v = (tid >= o) ? buf[tid - o] : 0;
        __syncthreads();
        buf[tid] += v;
        __syncthreads();
    }
    int run = (tid > 0) ? buf[tid - 1] : 0;
    for (int i = s0; i < s1; ++i) {
        off[i] = run;
        cur[i] = run;
        run += deg[i];
    }
    if (tid == 255) off[N_NODES] = buf[255];
}

__global__ __launch_bounds__(256) void scatter_kernel(const int* __restrict__ srcIdx,
                                                      const int* __restrict__ dstIdx,
                                                      int* __restrict__ curD,
                                                      int* __restrict__ curS,
                                                      int* __restrict__ sd_ea,
                                                      int* __restrict__ sd_src,
                                                      int* __restrict__ ss_dst) {
    int e = blockIdx.x * 256 + threadIdx.x;
    if (e >= N_EDGES) return;
    int s = srcIdx[e], d = dstIdx[e];
    int p = atomicAdd(&curD[d], 1);
    sd_ea[p] = e;
    sd_src[p] = s;
    int p2 = atomicAdd(&curS[s], 1);
    ss_dst[p2] = d;
}

// ---- GEMM: out[M,C] = A[M,128] @ B + bias. flags: 1=out bf16, 2=A bf16 ----
__global__ __launch_bounds__(256) void gemm_mfma(const void* __restrict__ Ap,
                                                 const u16* __restrict__ PB,
                                                 const float* __restrict__ bias,
                                                 void* __restrict__ outp,
                                                 int M, int Ctiles, int flags) {
    int tid = threadIdx.x;
    int wave = tid >> 6;
    int lane = tid & 63;
    int strip = blockIdx.x * 4 + wave;
    int row0 = strip * 16;
    if (row0 >= M) return;
    int q = lane >> 4, n = lane & 15;
    int C = Ctiles * 16;

    short8 a[4];
    if (flags & 2) {
        const u16* ap = (const u16*)Ap + (size_t)(row0 + n) * 128 + q * 8;
#pragma unroll
        for (int c = 0; c < 4; ++c) a[c] = *(const short8*)(ap + c * 32);
    } else {
        const float* ap = (const float*)Ap + (size_t)(row0 + n) * 128 + q * 8;
#pragma unroll
        for (int c = 0; c < 4; ++c) {
            f32x4 f0 = *(const f32x4*)(ap + c * 32);
            f32x4 f1 = *(const f32x4*)(ap + c * 32 + 4);
            short8 t;
#pragma unroll
            for (int j = 0; j < 4; ++j) {
                t[j] = (short)f2bf(f0[j]);
                t[4 + j] = (short)f2bf(f1[j]);
            }
            a[c] = t;
        }
    }

    for (int t = 0; t < Ctiles; ++t) {
        f32x4 acc = {0.f, 0.f, 0.f, 0.f};
#pragma unroll
        for (int c = 0; c < 4; ++c) {
            short8 b = *(const short8*)(PB + (((size_t)t * 4 + c) * 64 + lane) * 8);
            acc = __builtin_amdgcn_mfma_f32_16x16x32_bf16(a[c], b, acc, 0, 0, 0);
        }
        int col = t * 16 + n;
        float bv = bias ? bias[col] : 0.f;
#pragma unroll
        for (int r = 0; r < 4; ++r) {
            int row = row0 + q * 4 + r;
            float v = acc[r] + bv;
            if (flags & 1)
                ((u16*)outp)[(size_t)row * C + col] = f2bf(v);
            else
                ((float*)outp)[(size_t)row * C + col] = v;
        }
    }
}

// ---- fused aggregation: one wave per dst node, edges sorted by dst ----
// agg[n] = sum_{e in seg(n)} silu( EA[e]@W3 + T1a[n] + T1b[src_e] )   (bf16 out)
__global__ __launch_bounds__(256) void agg_fused(const float* __restrict__ EA,
                                                 const u16* __restrict__ PB3,
                                                 const int* __restrict__ offD,
                                                 const int* __restrict__ sd_ea,
                                                 const int* __restrict__ sd_src,
                                                 const u16* __restrict__ T1,
                                                 u16* __restrict__ agg) {
    int tid = threadIdx.x;
    int wave = tid >> 6;
    int lane = tid & 63;
    int node = blockIdx.x * 4 + wave;
    if (node >= N_NODES) return;
    int q = lane >> 4, n = lane & 15;
    int segS = offD[node], segE = offD[node + 1];

    float g1[8], rowAcc[8];
#pragma unroll
    for (int t = 0; t < 8; ++t) {
        g1[t] = bf2f(T1[(size_t)node * 256 + t * 16 + n]);
        rowAcc[t] = 0.f;
    }

    for (int base = segS; base < segE; base += 16) {
        int er = base + n;
        if (er > segE - 1) er = segE - 1;  // clamp: duplicate row, masked below
        const float* ap = EA + (size_t)sd_ea[er] * 128 + q * 8;
        short8 a[4];
#pragma unroll
        for (int c = 0; c < 4; ++c) {
            f32x4 f0 = *(const f32x4*)(ap + c * 32);
            f32x4 f1 = *(const f32x4*)(ap + c * 32 + 4);
            short8 t;
#pragma unroll
            for (int j = 0; j < 4; ++j) {
                t[j] = (short)f2bf(f0[j]);
                t[4 + j] = (short)f2bf(f1[j]);
            }
            a[c] = t;
        }
        int srow[4];
        bool val[4];
#pragma unroll
        for (int r = 0; r < 4; ++r) {
            int idx = base + q * 4 + r;
            val[r] = idx < segE;
            srow[r] = val[r] ? sd_src[idx] : 0;
        }
#pragma unroll
        for (int t = 0; t < 8; ++t) {
            f32x4 acc = {0.f, 0.f, 0.f, 0.f};
#pragma unroll
            for (int c = 0; c < 4; ++c) {
                short8 b = *(const short8*)(PB3 + (((size_t)t * 4 + c) * 64 + lane) * 8);
                acc = __builtin_amdgcn_mfma_f32_16x16x32_bf16(a[c], b, acc, 0, 0, 0);
            }
            int col = t * 16 + n;
#pragma unroll
            for (int r = 0; r < 4; ++r) {
                float v = acc[r] + g1[t] + bf2f(T1[(size_t)srow[r] * 256 + 128 + col]);
                float m = v / (1.f + __expf(-v));  // SiLU
                rowAcc[t] += val[r] ? m : 0.f;
            }
        }
    }
    // reduce over the 4 quads (rows) -> full column sums
#pragma unroll
    for (int t = 0; t < 8; ++t) {
        float v = rowAcc[t];
        v += __shfl_xor(v, 16, 64);
        v += __shfl_xor(v, 32, 64);
        if (lane < 16) agg[(size_t)node * 128 + t * 16 + lane] = f2bf(v);
    }
}

// ---- attention sum: one wave per src node, edges sorted by src ----
// attn[n] = sum_{e in segS(n)} h[dst_e]   (h bf16 -> f32)
__global__ __launch_bounds__(256) void attn_gather(const int* __restrict__ offS,
                                                   const int* __restrict__ ss_dst,
                                                   const u16* __restrict__ h,
                                                   float* __restrict__ attn) {
    int tid = threadIdx.x;
    int wave = tid >> 6;
    int lane = tid & 63;
    int node = blockIdx.x * 4 + wave;
    if (node >= N_NODES) return;
    int e0 = offS[node], e1 = offS[node + 1];
    float a0 = 0.f, a1 = 0.f;
    int d_next = (e0 < e1) ? ss_dst[e0] : 0;
    for (int e = e0; e < e1;) {
        int d = d_next;
        ++e;
        d_next = (e < e1) ? ss_dst[e] : 0;
        u32 hv = *(const u32*)(h + (size_t)d * 128 + lane * 2);
        a0 += bf2f((u16)(hv & 0xFFFFu));
        a1 += bf2f((u16)(hv >> 16));
    }
    f32x2 o;
    o[0] = a0;
    o[1] = a1;
    *(f32x2*)(attn + (size_t)node * 128 + lane * 2) = o;
}

extern "C" void kernel_launch(void* const* d_in, const int* in_sizes, int n_in,
                              void* d_out, int out_size, void* d_ws, size_t ws_size,
                              hipStream_t stream) {
    const float* x  = (const float*)d_in[0];
    const int* ei   = (const int*)d_in[1];
    const float* ea = (const float*)d_in[2];
    const float* We = (const float*)d_in[3];
    const float* be = (const float*)d_in[4];
    const float* Wg = (const float*)d_in[5];
    const float* bg = (const float*)d_in[6];
    // d_in[7]=Wa, d_in[8]=ba: dead — softmax over a size-1 axis is identically 1
    const float* Wo = (const float*)d_in[9];
    const float* bo = (const float*)d_in[10];
    float* out = (float*)d_out;

    const int* srcIdx = ei;            // edge_index[0]
    const int* dstIdx = ei + N_EDGES;  // edge_index[1]

    char* ws = (char*)d_ws;
    // layout (bytes), total ~62.3 MB
    u16*   PB1    = (u16*)(ws + 0);          // 64 KiB  [W1|W2] 16 tiles
    u16*   PB3    = (u16*)(ws + 65536);      // 32 KiB
    u16*   PBg    = (u16*)(ws + 98304);      // 32 KiB
    u16*   PBo    = (u16*)(ws + 131072);     // 32 KiB
    float* bias256 = (float*)(ws + 163840);  // 1 KiB
    u16*   T1     = (u16*)(ws + 262144);     // [N,256] bf16, 25.6 MB
    float* attn   = (float*)(ws + 262144);   // alias: T1 dead after agg_fused
    u16*   agg    = (u16*)(ws + 25862144);   // [N,128] bf16, 12.8 MB
    u16*   hbuf   = (u16*)(ws + 38662144);   // [N,128] bf16, 12.8 MB
    int*   degD   = (int*)(ws + 51462144);   // 200 KB
    int*   degS   = (int*)(ws + 51662144);   // 200 KB
    int*   offD   = (int*)(ws + 51862144);   // 200 KB (+pad)
    int*   offS   = (int*)(ws + 52062160);
    int*   curD   = (int*)(ws + 52262176);
    int*   curS   = (int*)(ws + 52462176);
    int*   sd_ea  = (int*)(ws + 52662176);   // 3.2 MB: edge id, sorted by dst
    int*   sd_src = (int*)(ws + 55862176);   // 3.2 MB: src,    sorted by dst
    int*   ss_dst = (int*)(ws + 59062176);   // 3.2 MB: dst,    sorted by src

    hipMemsetAsync(degD, 0, 400000, stream);  // degD + degS (contiguous)

    pack_b<<<8, 256, 0, stream>>>(We, PB1, 0);
    pack_b<<<8, 256, 0, stream>>>(We + 128 * 128, PB1, 8);
    pack_b<<<8, 256, 0, stream>>>(We + 2 * 128 * 128, PB3, 0);
    pack_b<<<8, 256, 0, stream>>>(Wg, PBg, 0);
    pack_b<<<8, 256, 0, stream>>>(Wo, PBo, 0);
    build_bias256<<<1, 256, 0, stream>>>(be, bias256);

    // counting sorts: by dst (agg) and by src (attn)
    hist_kernel<<<3125, 256, 0, stream>>>(srcIdx, dstIdx, degD, degS);
    scan_kernel<<<1, 256, 0, stream>>>(degD, offD, curD);
    scan_kernel<<<1, 256, 0, stream>>>(degS, offS, curS);
    scatter_kernel<<<3125, 256, 0, stream>>>(srcIdx, dstIdx, curD, curS, sd_ea, sd_src, ss_dst);

    // T1 = [x@W1 + be | x@W2]  (bf16)
    gemm_mfma<<<782, 256, 0, stream>>>(x, PB1, bias256, T1, N_NODES, 16, 1);

    // agg[n] = sum over dst-segment of silu(...)  — no atomics
    agg_fused<<<12500, 256, 0, stream>>>(ea, PB3, offD, sd_ea, sd_src, T1, agg);

    // h = agg@Wg + bg  (bf16 in, bf16 out)
    gemm_mfma<<<782, 256, 0, stream>>>(agg, PBg, bg, hbuf, N_NODES, 8, 3);

    // attn[n] = sum over src-segment of h[dst]  — no atomics (writes over T1)
    attn_gather<<<12500, 256, 0, stream>>>(offS, ss_dst, hbuf, attn);

    // out = attn@Wo + bo  (f32)
    gemm_mfma<<<782, 256, 0, stream>>>(attn, PBo, bo, out, N_NODES, 8, 0);

    (void)in_sizes; (void)n_in; (void)out_size; (void)ws_size;
}